// Round 9
// baseline (777.985 us; speedup 1.0000x reference)
//
#include <hip/hip_runtime.h>
#include <math.h>

// ---------------- MS-SSIM on MI355X, round 11 ----------------
// Request-minimal layout: each lane owns 4 cols, ONE aligned dwordx4 per
// image per row (2 loads/row vs 6 dwordx2 before; exact bytes, no horizontal
// over-read). V-first separable conv (raw x,z 5-row window = 40 VGPR);
// horizontal conv gets +-2 halo by shuffling the V-conv results (16
// bpermutes/row, LDS pipe). 252-col output strips (loads 16B-aligned,
// strips overlap 4 cols; per-element ownership masks keep sums/pool exact).
// Small levels at TROWS=1 for wave-count parallelism in the tail.

typedef float f2 __attribute__((ext_vector_type(2)));
typedef float f4 __attribute__((ext_vector_type(4)));

static __device__ __forceinline__ f2 vfma2(f2 a, f2 b, f2 c) {
    return __builtin_elementwise_fma(a, b, c);
}
static __device__ __forceinline__ f4 vfma4(f4 a, f4 b, f4 c) {
    return __builtin_elementwise_fma(a, b, c);
}

#define C1F 0.0001f
#define C2F 0.0009f
// normalized Gaussian, WIN=5, sigma=1.5
#define GW0f 0.12007838f
#define GW1f 0.23388060f
#define GW2f 0.29208204f

// Vertical 5-tap conv over raw-row window (static slots), f4.
#define VCONV4(OUT, WN, S0,S1,S2,S3,S4) do { \
    const f4 t_ = WN[S0] + WN[S4]; \
    const f4 u_ = WN[S1] + WN[S3]; \
    (OUT) = vfma4(u_, G1q, vfma4(t_, G0q, WN[S2] * G2q)); \
} while (0)

// Vertical conv of (x^2 + z^2) computed on the fly from raw windows.
#define VQCONV4(OUT, WX, WZ, S0,S1,S2,S3,S4) do { \
    f4 t1_ = vfma4(WX[S0], WX[S0], WX[S4] * WX[S4]); \
    t1_ = vfma4(WZ[S0], WZ[S0], t1_); t1_ = vfma4(WZ[S4], WZ[S4], t1_); \
    f4 t2_ = vfma4(WX[S1], WX[S1], WX[S3] * WX[S3]); \
    t2_ = vfma4(WZ[S1], WZ[S1], t2_); t2_ = vfma4(WZ[S3], WZ[S3], t2_); \
    const f4 t3_ = vfma4(WZ[S2], WZ[S2], WX[S2] * WX[S2]); \
    (OUT) = vfma4(t2_, G1q, vfma4(t1_, G0q, t3_ * G2q)); \
} while (0)

// Vertical conv of (x*z) computed on the fly.
#define VPCONV4(OUT, WX, WZ, S0,S1,S2,S3,S4) do { \
    const f4 t1_ = vfma4(WX[S0], WZ[S0], WX[S4] * WZ[S4]); \
    const f4 t2_ = vfma4(WX[S1], WZ[S1], WX[S3] * WZ[S3]); \
    const f4 t3_ = WX[S2] * WZ[S2]; \
    (OUT) = vfma4(t2_, G1q, vfma4(t1_, G0q, t3_ * G2q)); \
} while (0)

// Horizontal 5-tap conv for an output f2 pair from VL/V01/VR f2s.
#define HCONV(DST, VL, V01, VR) do { \
    const f2 t1_ = (VL) + (VR); \
    f2 mid_; mid_.x = (VL).y + (V01).y; mid_.y = (V01).x + (VR).x; \
    (DST) = vfma2(mid_, G1p, vfma2(t1_, G0p, (V01) * G2p)); \
} while (0)

#define SSIM_PX2(A,B,Q,P, SS, CC) do { \
    const f2 ab_ = (A) * (B); \
    const f2 a2b2_ = vfma2((B), (B), (A) * (A)); \
    const f2 s12_ = vfma2(TWOp, (P) - ab_, C2p); \
    const f2 sden_ = ((Q) - a2b2_) + C2p; \
    const f2 d1_ = a2b2_ + C1p; \
    const f2 n1_ = vfma2(TWOp, ab_, C1p); \
    const f2 den_ = d1_ * sden_; \
    f2 rd_; \
    rd_.x = __builtin_amdgcn_rcpf(den_.x); \
    rd_.y = __builtin_amdgcn_rcpf(den_.y); \
    (SS) = n1_ * s12_ * rd_; \
    (CC) = s12_ * d1_ * rd_; \
} while (0)

// One row step. I = step index (compile-time). S0..S4 = window slots of
// rows I-4..I (row I stored into S4).
#define STEP(I, S0,S1,S2,S3,S4) do { \
    const int r_in = y0 + (I) - 2; \
    const int rc_ = min(max(r_in, 0), H - 1); \
    const float rv_ = ((unsigned)r_in < (unsigned)H) ? 1.f : 0.f; \
    const f4 m_ = mE * rv_; \
    wx[S4] = *(const f4*)(p1 + (size_t)rc_ * W + lc) * m_; \
    wz[S4] = *(const f4*)(p2 + (size_t)rc_ * W + lc) * m_; \
    if ((I) >= 4) { \
        f4 vx, vz, vq, vp; \
        VCONV4(vx, wx, S0,S1,S2,S3,S4); \
        VCONV4(vz, wz, S0,S1,S2,S3,S4); \
        VQCONV4(vq, wx, wz, S0,S1,S2,S3,S4); \
        VPCONV4(vp, wx, wz, S0,S1,S2,S3,S4); \
        f2 ux, uz, uq, up, dx, dz, dq, dp; \
        ux.x = __shfl_up(vx.z, 1);   ux.y = __shfl_up(vx.w, 1); \
        uz.x = __shfl_up(vz.z, 1);   uz.y = __shfl_up(vz.w, 1); \
        uq.x = __shfl_up(vq.z, 1);   uq.y = __shfl_up(vq.w, 1); \
        up.x = __shfl_up(vp.z, 1);   up.y = __shfl_up(vp.w, 1); \
        dx.x = __shfl_down(vx.x, 1); dx.y = __shfl_down(vx.y, 1); \
        dz.x = __shfl_down(vz.x, 1); dz.y = __shfl_down(vz.y, 1); \
        dq.x = __shfl_down(vq.x, 1); dq.y = __shfl_down(vq.y, 1); \
        dp.x = __shfl_down(vp.x, 1); dp.y = __shfl_down(vp.y, 1); \
        ux *= upM; uz *= upM; uq *= upM; up *= upM; \
        const f2 vxa = vx.xy, vxb = vx.zw; \
        const f2 vza = vz.xy, vzb = vz.zw; \
        const f2 vqa = vq.xy, vqb = vq.zw; \
        const f2 vpa = vp.xy, vpb = vp.zw; \
        f2 A0, A1, B0, B1, Q0, Q1, P0, P1; \
        HCONV(A0, ux, vxa, vxb);  HCONV(A1, vxa, vxb, dx); \
        HCONV(B0, uz, vza, vzb);  HCONV(B1, vza, vzb, dz); \
        HCONV(Q0, uq, vqa, vqb);  HCONV(Q1, vqa, vqb, dq); \
        HCONV(P0, up, vpa, vpb);  HCONV(P1, vpa, vpb, dp); \
        f2 ss_, cc_; \
        SSIM_PX2(A0, B0, Q0, P0, ss_, cc_); \
        ACCS0 += ss_ * mO01;  ACCC0 += cc_ * mO01; \
        SSIM_PX2(A1, B1, Q1, P1, ss_, cc_); \
        ACCS1 += ss_ * mO23;  ACCC1 += cc_ * mO23; \
    } \
    { \
        const bool pc_ = (TROWS == 1) ? ((I) == 2 && (y0 & 1)) \
                         : (((I) & 1) && (I) >= 3 && (I) <= TROWS + 1); \
        if (q1 && pc_) { \
            const f4 tx_ = wx[S4] + wx[S3]; \
            const f4 tz_ = wz[S4] + wz[S3]; \
            const size_t po_ = (size_t)(r_in >> 1) * WP + (c0 >> 1); \
            if (pOwn0) { q1[po_]   = (tx_.x + tx_.y) * 0.25f; \
                         q2[po_]   = (tz_.x + tz_.y) * 0.25f; } \
            if (pOwn2) { q1[po_+1] = (tx_.z + tx_.w) * 0.25f; \
                         q2[po_+1] = (tz_.z + tz_.w) * 0.25f; } \
        } \
    } \
} while (0)

#define BATCH5(T) do { \
    STEP((T)*5+0, 1,2,3,4,0); \
    STEP((T)*5+1, 2,3,4,0,1); \
    STEP((T)*5+2, 3,4,0,1,2); \
    STEP((T)*5+3, 4,0,1,2,3); \
    STEP((T)*5+4, 0,1,2,3,4); \
} while (0)

template<int TROWS, int WPB, int H, int W, int SX>
__global__ __launch_bounds__(WPB * 64, 3)
void ssim_level_kernel(const float* __restrict__ img1,
                       const float* __restrict__ img2,
                       float* __restrict__ pool1,
                       float* __restrict__ pool2,
                       double* __restrict__ block_out)
{
    constexpr int SY = H / TROWS;
    constexpr int spp = SX * SY;
    constexpr int ITERS = TROWS + 4;
    constexpr int NB = ITERS / 5;
    static_assert(ITERS % 5 == 0, "TROWS+4 must be divisible by 5");
    static_assert(NB == 1 || NB == 4, "written for NB in {1,4}");
    constexpr int WP = W >> 1;

    const int lane = threadIdx.x & 63;
    const int wv   = threadIdx.x >> 6;
    const int w    = blockIdx.x * WPB + wv;

    const int plane = w / spp;
    const int rem   = w - plane * spp;
    const int sy    = rem / SX;
    const int sx    = rem - sy * SX;

    const int base = sx * 252;              // output strip [base+2, base+253]
    const int y0   = sy * TROWS;
    const int c0   = base + 4 * lane;       // lane loads cols c0..c0+3 (16B aligned)
    const int lc   = min(c0, W - 4);        // clamped, stays 16B aligned
    const bool lastStrip = (sx == SX - 1);

    // per-element input-validity mask (col < W)
    f4 mE;
    mE.x = (c0 + 0 < W) ? 1.f : 0.f;
    mE.y = (c0 + 1 < W) ? 1.f : 0.f;
    mE.z = (c0 + 2 < W) ? 1.f : 0.f;
    mE.w = (c0 + 3 < W) ? 1.f : 0.f;
    // per-element output-ownership mask
    float oOK[4];
    #pragma unroll
    for (int j = 0; j < 4; ++j) {
        const int cj = c0 + j;
        const bool own = (cj < W) &&
                         (base == 0 || cj >= base + 2) &&
                         (cj <= base + 253 || lastStrip);
        oOK[j] = own ? 1.f : 0.f;
    }
    f2 mO01; mO01.x = oOK[0]; mO01.y = oOK[1];
    f2 mO23; mO23.x = oOK[2]; mO23.y = oOK[3];
    const bool pOwn0 = (oOK[0] != 0.f) && (oOK[1] != 0.f);
    const bool pOwn2 = (oOK[2] != 0.f) && (oOK[3] != 0.f);
    // zero the up-halo only where it must be image zero-padding
    const float upM = (lane == 0 && base == 0) ? 0.f : 1.f;

    const float* p1 = img1 + (size_t)plane * (H * W);
    const float* p2 = img2 + (size_t)plane * (H * W);
    float* q1 = pool1 ? pool1 + (size_t)plane * (H >> 1) * WP : nullptr;
    float* q2 = pool2 ? pool2 + (size_t)plane * (H >> 1) * WP : nullptr;

    const f4 G0q = {GW0f, GW0f, GW0f, GW0f};
    const f4 G1q = {GW1f, GW1f, GW1f, GW1f};
    const f4 G2q = {GW2f, GW2f, GW2f, GW2f};
    const f2 G0p = {GW0f, GW0f};
    const f2 G1p = {GW1f, GW1f};
    const f2 G2p = {GW2f, GW2f};
    const f2 C1p = {C1F, C1F};
    const f2 C2p = {C2F, C2F};
    const f2 TWOp = {2.f, 2.f};

    f4 wx[5], wz[5];                        // raw-row rolling window
    f2 ACCS0 = {0.f,0.f}, ACCS1 = {0.f,0.f};
    f2 ACCC0 = {0.f,0.f}, ACCC1 = {0.f,0.f};

    if constexpr (NB == 4) {
        BATCH5(0); BATCH5(1); BATCH5(2); BATCH5(3);
    } else {
        BATCH5(0);
    }

    float accs = ACCS0.x + ACCS0.y + ACCS1.x + ACCS1.y;
    float accc = ACCC0.x + ACCC0.y + ACCC1.x + ACCC1.y;
    #pragma unroll
    for (int o = 32; o > 0; o >>= 1) {
        accs += __shfl_down(accs, o, 64);
        accc += __shfl_down(accc, o, 64);
    }

    __shared__ double sred[WPB][2];
    if (lane == 0) { sred[wv][0] = (double)accs; sred[wv][1] = (double)accc; }
    __syncthreads();
    if (threadIdx.x == 0) {
        double s = 0.0, c = 0.0;
        #pragma unroll
        for (int k = 0; k < WPB; ++k) { s += sred[k][0]; c += sred[k][1]; }
        block_out[2 * (size_t)blockIdx.x]     = s;
        block_out[2 * (size_t)blockIdx.x + 1] = c;
    }
}

// per-level block counts / slot offsets (one double2 slot per block)
static constexpr int NBLK[5] = {2304, 768, 3072, 1536, 768};
static constexpr int BOFF[5] = {0, 2304, 3072, 6144, 7680};   // total 8448

__global__ __launch_bounds__(1024)
void ssim_final_kernel(const double* __restrict__ bsum, float* __restrict__ out)
{
    __shared__ double partial[16][2];
    __shared__ double lvl[5][2];
    const double npx[5] = {96.0*512*512, 96.0*256*256, 96.0*128*128,
                           96.0*64*64,   96.0*32*32};
    const int tid = threadIdx.x, lane = tid & 63, wv = tid >> 6;

    for (int l = 0; l < 5; ++l) {
        double s = 0.0, c = 0.0;
        for (int k = tid; k < NBLK[l]; k += 1024) {
            s += bsum[2 * (size_t)(BOFF[l] + k)];
            c += bsum[2 * (size_t)(BOFF[l] + k) + 1];
        }
        #pragma unroll
        for (int o = 32; o > 0; o >>= 1) {
            s += __shfl_down(s, o, 64);
            c += __shfl_down(c, o, 64);
        }
        if (lane == 0) { partial[wv][0] = s; partial[wv][1] = c; }
        __syncthreads();
        if (tid == 0) {
            double ts = 0.0, tc = 0.0;
            for (int k = 0; k < 16; ++k) { ts += partial[k][0]; tc += partial[k][1]; }
            lvl[l][0] = ts / npx[l];
            lvl[l][1] = tc / npx[l];
        }
        __syncthreads();
    }
    if (tid == 0) {
        const double wgt[5] = {0.0448, 0.2856, 0.3001, 0.2363, 0.1333};
        double ssim4 = (lvl[4][0] + 1.0) * 0.5;
        double P = pow(ssim4, wgt[4]);
        double r = pow((lvl[0][1] + 1.0) * 0.5, wgt[0]) *
                   pow((lvl[1][1] + 1.0) * 0.5, wgt[1]) *
                   pow((lvl[2][1] + 1.0) * 0.5, wgt[2]) *
                   pow((lvl[3][1] + 1.0) * 0.5, wgt[3]);
        r *= P * P * P * P;
        out[0] = (float)r;
    }
}

extern "C" void kernel_launch(void* const* d_in, const int* in_sizes, int n_in,
                              void* d_out, int out_size, void* d_ws, size_t ws_size,
                              hipStream_t stream)
{
    const float* img1 = (const float*)d_in[0];
    const float* img2 = (const float*)d_in[1];
    float* out = (float*)d_out;

    char* ws = (char*)d_ws;
    double* wsum = (double*)ws;                 // 8448 double2 slots (135 KB)
    size_t off = 524288;                        // pooled arrays after 512 KB
    const size_t P = 96;
    float* l1a = (float*)(ws + off); off += P * 256 * 256 * sizeof(float);
    float* l1b = (float*)(ws + off); off += P * 256 * 256 * sizeof(float);
    float* l2a = (float*)(ws + off); off += P * 128 * 128 * sizeof(float);
    float* l2b = (float*)(ws + off); off += P * 128 * 128 * sizeof(float);
    float* l3a = (float*)(ws + off); off += P * 64 * 64 * sizeof(float);
    float* l3b = (float*)(ws + off); off += P * 64 * 64 * sizeof(float);
    float* l4a = (float*)(ws + off); off += P * 32 * 32 * sizeof(float);
    float* l4b = (float*)(ws + off); off += P * 32 * 32 * sizeof(float);

    // L0: 512x512, TROWS=16, SX=3, SY=32 -> 9216 waves, 2304 blocks
    ssim_level_kernel<16, 4, 512, 512, 3><<<2304, 256, 0, stream>>>(
        img1, img2, l1a, l1b, wsum + 2 * (size_t)BOFF[0]);
    // L1: 256x256, TROWS=16, SX=2, SY=16 -> 3072 waves, 768 blocks
    ssim_level_kernel<16, 4, 256, 256, 2><<<768, 256, 0, stream>>>(
        l1a, l1b, l2a, l2b, wsum + 2 * (size_t)BOFF[1]);
    // L2: 128x128, TROWS=1, SX=1, SY=128 -> 12288 waves, 3072 blocks
    ssim_level_kernel<1, 4, 128, 128, 1><<<3072, 256, 0, stream>>>(
        l2a, l2b, l3a, l3b, wsum + 2 * (size_t)BOFF[2]);
    // L3: 64x64, TROWS=1, SX=1, SY=64 -> 6144 waves, 1536 blocks
    ssim_level_kernel<1, 4, 64, 64, 1><<<1536, 256, 0, stream>>>(
        l3a, l3b, l4a, l4b, wsum + 2 * (size_t)BOFF[3]);
    // L4: 32x32, TROWS=1, SX=1, SY=32 -> 3072 waves, 768 blocks, no pooling
    ssim_level_kernel<1, 4, 32, 32, 1><<<768, 256, 0, stream>>>(
        l4a, l4b, nullptr, nullptr, wsum + 2 * (size_t)BOFF[4]);

    ssim_final_kernel<<<1, 1024, 0, stream>>>(wsum, out);
}